// Round 18
// baseline (69.867 us; speedup 1.0000x reference)
//
#include <hip/hip_runtime.h>
#include <hip/hip_bf16.h>

// DeformConv2d: x[4,4,256,36,36] f32, filter[1024,256,3,3] f32, offset[16,2] f32
// out[4,1024,36,36] f32.
// R18 = R17 (best, 67.3us) with the xr bank-conflict ACTUALLY fixed:
//   row pitch 64 -> 68 words (272B, 16B-aligned). Pitch mod 32 = 4, so each row
//   step shifts banks by 4: phase-2's 8x8 (xi,c8) b128 reads cover all 32 banks
//   (~2-way, free); phase-1 same-c write group 9-way -> ~4-way. XOR swizzle
//   removed (derivation showed it canceled under bank = addr%32 with pitch 64).
// gemm: 128x64, dbuf, counted-vmcnt(6) -- UNTOUCHED (R8-proven).
// K layout k' = n*256+c. ws = 100,270,080 B.

#define HH 36
#define WW 36
#define CT 256
#define NB 16
#define KK 2304      // 9*256
#define NP 1296      // 36*36
#define OCH 1024
#define OUTG 256
#define SAMPLE_BLOCKS (NB * HH * 2)    // 1152
#define XP 68                          // xr row pitch in floats (68%32=4)

typedef __attribute__((ext_vector_type(8))) short short8;
typedef __attribute__((ext_vector_type(4))) float f32x4;
typedef __attribute__((ext_vector_type(4))) unsigned short us4;
typedef __attribute__((ext_vector_type(4))) unsigned uint4v;

__device__ __forceinline__ unsigned short f2bf(float v) {
    unsigned u = __float_as_uint(v);
    u += 0x7fffu + ((u >> 16) & 1u);   // RNE
    return (unsigned short)(u >> 16);
}
__device__ __forceinline__ unsigned pk2bf(float lo, float hi) {
    __hip_bfloat162 h = __float22bfloat162_rn(float2{lo, hi});   // v_cvt_pk_bf16_f32
    return *reinterpret_cast<unsigned*>(&h);
}

// ---------------- kernel 2: sampling -> Xoff^T bf16, + merged filter cvt ----------
// blocks [0,1152): sample, 16b * 36y * 2 half(128ch), XCD-swizzled.
// blocks [1152,2176): filter fp32 [o][c*9+n] -> bf16 [o][n*256+c], o = bx-1152.
__global__ __launch_bounds__(256) void sample_kernel(const float* __restrict__ x,
                                                     const float* __restrict__ tf,
                                                     const float* __restrict__ off,
                                                     unsigned short* __restrict__ xt,
                                                     unsigned short* __restrict__ wbf) {
    const int bx = blockIdx.x;
    if (bx >= SAMPLE_BLOCKS) {                 // ---- cvt path (no LDS, no barriers)
        const int o = bx - SAMPLE_BLOCKS;
        const float* fo = tf + (size_t)o * KK;
        unsigned short* wo = wbf + (size_t)o * KK;
        for (int k4 = threadIdx.x * 4; k4 < KK; k4 += 1024) {
            int n = k4 >> 8;
            int c = k4 & 255;
            us4 v;
#pragma unroll
            for (int cc = 0; cc < 4; ++cc) v[cc] = f2bf(fo[(c + cc) * 9 + n]);
            *reinterpret_cast<us4*>(wo + k4) = v;
        }
        return;
    }

    const int wid = (bx & 7) * 144 + (bx >> 3);
    const int b = wid / 72;
    const int rem = wid - b * 72;
    const int y = rem >> 1;
    const int half = rem & 1;
    const int tid = threadIdx.x;
    const float sx = 3.0f / off[2 * b + 0];
    const float sy = 3.0f / off[2 * b + 1];

    // row (i) tables: per-thread registers (block-uniform)
    int qxl[3], qxr[3]; float gxl[3], gxr[3];
    bool lok[3], rok[3];
#pragma unroll
    for (int i = 0; i < 3; ++i) {
        float px = (float)(y + 1) + (float)(i - 1) * sx;
        float pc = fminf(fmaxf(px, 0.f), 37.f);
        float fl = floorf(px);
        float ql = fminf(fmaxf(fl, 0.f), 37.f);
        float qr = fminf(fmaxf(fl + 1.f, 0.f), 37.f);
        qxl[i] = (int)ql; qxr[i] = (int)qr;
        gxl[i] = 1.f + (ql - pc);
        gxr[i] = 1.f - (qr - pc);
        lok[i] = (qxl[i] >= 1 && qxl[i] <= 36);
        rok[i] = (qxr[i] >= 1 && qxr[i] <= 36);
    }

    // column (x,j) tables in LDS
    __shared__ int   s_qyl[HH * 3], s_qyr[HH * 3];
    __shared__ float s_gyl[HH * 3], s_gyr[HH * 3];
    if (tid < HH * 3) {
        int xx = tid / 3, j = tid % 3;
        float py = (float)(xx + 1) + (float)(j - 1) * sy;
        float pc = fminf(fmaxf(py, 0.f), 37.f);
        float fl = floorf(py);
        float ql = fminf(fmaxf(fl, 0.f), 37.f);
        float qr = fminf(fmaxf(fl + 1.f, 0.f), 37.f);
        s_qyl[tid] = (int)ql; s_qyr[tid] = (int)qr;
        s_gyl[tid] = 1.f + (ql - pc);
        s_gyr[tid] = 1.f - (qr - pc);
    }

    // row-lerped tile: xr[i][col 0..37][c 0..63], pitch XP=68 (pad words unread)
    __shared__ __align__(16) float xr[3 * 38 * XP];

    for (int chunk = 0; chunk < 2; ++chunk) {
        const int c0 = half * 128 + chunk * 64;
        __syncthreads();      // xr reusable (prev phase-2 done); covers tables iter0

        // boundary cols 0 and 37 are zero (zero padding)
        for (int t = tid; t < 384; t += 256) {
            int i = t / 128, r3 = t & 127;
            int col = (r3 & 64) ? 37 : 0, c = r3 & 63;
            xr[(i * 38 + col) * XP + c] = 0.f;
        }

        // phase 1: row-lerp. tasks (i, c, colquad): coalesced float4 col-reads,
        // 4 scalar LDS writes (row step => +4 banks with pitch 68).
        const float* xb = x + (size_t)(b * CT + c0) * NP;
        for (int t = tid; t < 3 * 64 * 9; t += 256) {
            const int i = t / 576;
            const int r2 = t - i * 576;
            const int c = r2 / 9;
            const int cq = r2 - c * 9;
            const int colb = 1 + cq * 4;          // padded col of elem 0
            const float* xc = xb + c * NP;
            float4 vl = make_float4(0.f, 0.f, 0.f, 0.f);
            float4 vr = vl;
            if (lok[i]) vl = *(const float4*)(xc + (qxl[i] - 1) * WW + colb - 1);
            if (rok[i]) vr = *(const float4*)(xc + (qxr[i] - 1) * WW + colb - 1);
            float* dst = &xr[(i * 38 + colb) * XP + c];
            dst[0]      = gxl[i] * vl.x + gxr[i] * vr.x;
            dst[XP]     = gxl[i] * vl.y + gxr[i] * vr.y;
            dst[2 * XP] = gxl[i] * vl.z + gxr[i] * vr.z;
            dst[3 * XP] = gxl[i] * vl.w + gxr[i] * vr.w;
        }
        __syncthreads();

        // phase 2 (rebalanced): subtasks (i, xi, c8) -> 3 taps x 8 channels each.
        for (int t = tid; t < 3 * 36 * 8; t += 256) {
            const int i = t / 288;
            const int r = t - i * 288;
            const int xi = r >> 3;
            const int c8 = r & 7;
            unsigned short* op = xt + ((size_t)b * NP + y * WW + xi) * KK + c0 + c8 * 8
                               + i * 3 * 256;
#pragma unroll
            for (int j = 0; j < 3; ++j) {
                const int tq = xi * 3 + j;
                const float gl = s_gyl[tq], gr = s_gyr[tq];
                const float* L = &xr[(i * 38 + s_qyl[tq]) * XP + c8 * 8];
                const float* R = &xr[(i * 38 + s_qyr[tq]) * XP + c8 * 8];
                f32x4 L0 = *(const f32x4*)L, L1 = *(const f32x4*)(L + 4);
                f32x4 R0 = *(const f32x4*)R, R1 = *(const f32x4*)(R + 4);
                uint4v w;
                w[0] = pk2bf(gl * L0[0] + gr * R0[0], gl * L0[1] + gr * R0[1]);
                w[1] = pk2bf(gl * L0[2] + gr * R0[2], gl * L0[3] + gr * R0[3]);
                w[2] = pk2bf(gl * L1[0] + gr * R1[0], gl * L1[1] + gr * R1[1]);
                w[3] = pk2bf(gl * L1[2] + gr * R1[2], gl * L1[3] + gr * R1[3]);
                *reinterpret_cast<uint4v*>(op + j * 256) = w;
            }
        }
    }
}

// ---------------- kernel 3: MFMA GEMM, 128x64, dbuf, counted-vmcnt (R8) ----------
__global__ __launch_bounds__(256) void gemm_kernel(const unsigned short* __restrict__ wbf,
                                                   const unsigned short* __restrict__ xt,
                                                   float* __restrict__ out) {
    // 672 blocks = 8 XCD * 84; 84 per XCD = 2 b's worth (42 tiles per b)
    const int wid = (blockIdx.x & 7) * 84 + (blockIdx.x >> 3);
    const int b = wid / 42;
    const int rem = wid - b * 42;
    const int mt = rem / 21;
    const int nt = rem - mt * 21;
    const int m0 = mt * 128;
    const int p0 = nt * 64;
    const int g = b & 3;
    const int mimg = b >> 2;

    const unsigned short* Ab = wbf + (size_t)(g * OUTG + m0) * KK;
    const unsigned short* Bb = xt + (size_t)b * NP * KK;

    __shared__ __align__(16) unsigned short As[2][128 * 64];
    __shared__ __align__(16) unsigned short Bs[2][64 * 64];

    const int tid = threadIdx.x;
    const int wave = tid >> 6, lane = tid & 63;
    const int wr = wave >> 1, wc = wave & 1;
    const int l8 = lane >> 3;
    const int sgrp = (lane & 7) ^ l8;         // pre-swizzled source column group

    f32x4 acc[4][2] = {};

#define STAGE(BUF, KT) do {                                                       \
    const int k0_ = (KT) * 64;                                                    \
    _Pragma("unroll")                                                             \
    for (int ii = 0; ii < 4; ++ii) {                                              \
        const int inst = wave * 4 + ii;                                           \
        const int row = inst * 8 + l8;                                            \
        const unsigned short* srcA = Ab + (size_t)row * KK + k0_ + sgrp * 8;      \
        __builtin_amdgcn_global_load_lds(                                         \
            (const __attribute__((address_space(1))) void*)srcA,                  \
            (__attribute__((address_space(3))) void*)&As[BUF][inst * 512], 16, 0, 0); \
    }                                                                             \
    _Pragma("unroll")                                                             \
    for (int ii = 0; ii < 2; ++ii) {                                              \
        const int inst = wave * 2 + ii;                                           \
        const int row = inst * 8 + l8;                                            \
        int prow = p0 + row;                                                      \
        prow = prow < NP ? prow : NP - 1;                                         \
        const unsigned short* srcB = Bb + (size_t)prow * KK + k0_ + sgrp * 8;     \
        __builtin_amdgcn_global_load_lds(                                         \
            (const __attribute__((address_space(1))) void*)srcB,                  \
            (__attribute__((address_space(3))) void*)&Bs[BUF][inst * 512], 16, 0, 0); \
    }                                                                             \
} while (0)

#define COMPUTE(BUF) do {                                                         \
    _Pragma("unroll")                                                             \
    for (int kk = 0; kk < 2; ++kk) {                                              \
        short8 a[4], bfr[2];                                                      \
        const int g8 = (((kk * 4) + (lane >> 4)) ^ (lane & 7)) << 3;              \
        const int rA = wr * 64 + (lane & 15);                                     \
        const int rB = wc * 32 + (lane & 15);                                     \
        _Pragma("unroll")                                                         \
        for (int m = 0; m < 4; ++m)                                               \
            a[m] = *(const short8*)&As[BUF][(rA + m * 16) * 64 + g8];             \
        _Pragma("unroll")                                                         \
        for (int n = 0; n < 2; ++n)                                               \
            bfr[n] = *(const short8*)&Bs[BUF][(rB + n * 16) * 64 + g8];           \
        _Pragma("unroll")                                                         \
        for (int m = 0; m < 4; ++m)                                               \
            _Pragma("unroll")                                                     \
            for (int n = 0; n < 2; ++n)                                           \
                acc[m][n] = __builtin_amdgcn_mfma_f32_16x16x32_bf16(              \
                    a[m], bfr[n], acc[m][n], 0, 0, 0);                            \
    }                                                                             \
} while (0)

    STAGE(0, 0);                         // 6 loads in flight

#pragma unroll 1
    for (int kt = 0; kt < 35; ++kt) {
        STAGE((kt + 1) & 1, kt + 1);     // +6 loads -> 12 in flight
        // wait ONLY for tile kt's 6 loads; kt+1's stay in flight across barrier
        asm volatile("s_waitcnt vmcnt(6)" ::: "memory");
        __builtin_amdgcn_sched_barrier(0);
        __builtin_amdgcn_s_barrier();    // all waves' tile-kt loads landed
        COMPUTE(kt & 1);
        __builtin_amdgcn_s_barrier();    // readers done before next STAGE overwrites
    }
    asm volatile("s_waitcnt vmcnt(0)" ::: "memory");
    __builtin_amdgcn_sched_barrier(0);
    __builtin_amdgcn_s_barrier();
    COMPUTE(35 & 1);

#undef STAGE
#undef COMPUTE

    float* ob = out + ((size_t)mimg * OCH + g * OUTG) * NP;
    const int o0 = m0 + wr * 64 + ((lane >> 4) << 2);
    const int pc = p0 + wc * 32 + (lane & 15);
#pragma unroll
    for (int n = 0; n < 2; ++n) {
        int p = pc + n * 16;
        if (p >= NP) continue;
#pragma unroll
        for (int m = 0; m < 4; ++m) {
#pragma unroll
            for (int r = 0; r < 4; ++r)
                ob[(size_t)(o0 + m * 16 + r) * NP + p] = acc[m][n][r];
        }
    }
}

extern "C" void kernel_launch(void* const* d_in, const int* in_sizes, int n_in,
                              void* d_out, int out_size, void* d_ws, size_t ws_size,
                              hipStream_t stream) {
    const float* x   = (const float*)d_in[0];
    const float* tf  = (const float*)d_in[1];
    const float* off = (const float*)d_in[2];
    float* out = (float*)d_out;

    unsigned short* xt  = (unsigned short*)d_ws;                    // [16][1296][2304] bf16
    unsigned short* wbf = xt + (size_t)NB * NP * KK;                // [1024][2304] bf16

    hipLaunchKernelGGL(sample_kernel, dim3(SAMPLE_BLOCKS + OCH), dim3(256), 0, stream,
                       x, tf, off, xt, wbf);
    hipLaunchKernelGGL(gemm_kernel, dim3(672), dim3(256), 0, stream, wbf, xt, out);
}

// Round 19
// 67.056 us; speedup vs baseline: 1.0419x; 1.0419x over previous
//
#include <hip/hip_runtime.h>
#include <hip/hip_bf16.h>

// DeformConv2d: x[4,4,256,36,36] f32, filter[1024,256,3,3] f32, offset[16,2] f32
// out[4,1024,36,36] f32.
// R19 = R17 verbatim (session best, 67.3us). R18's pitch-68 conflict fix reverted:
// it cut SQ_LDS_BANK_CONFLICT 6.2M->3.5M but crossed the 32KB LDS boundary
// (5 -> 4 blocks/CU) and net-regressed 2.6us -- sample is latency-bound, not
// conflict-bound.
//   sample launch: blocks [0,1152) deformable sampling (XCD-swizzled),
//                  blocks [1152,2176) filter fp32->bf16 K-reorder (merged cvt).
//   gemm: 128x64, dbuf, counted-vmcnt(6), 2 barriers/iter (R8-proven).
// K layout k' = n*256+c. ws = 100,270,080 B.

#define HH 36
#define WW 36
#define CT 256
#define NB 16
#define KK 2304      // 9*256
#define NP 1296      // 36*36
#define OCH 1024
#define OUTG 256
#define SAMPLE_BLOCKS (NB * HH * 2)    // 1152

typedef __attribute__((ext_vector_type(8))) short short8;
typedef __attribute__((ext_vector_type(4))) float f32x4;
typedef __attribute__((ext_vector_type(4))) unsigned short us4;
typedef __attribute__((ext_vector_type(4))) unsigned uint4v;

__device__ __forceinline__ unsigned short f2bf(float v) {
    unsigned u = __float_as_uint(v);
    u += 0x7fffu + ((u >> 16) & 1u);   // RNE
    return (unsigned short)(u >> 16);
}
__device__ __forceinline__ unsigned pk2bf(float lo, float hi) {
    __hip_bfloat162 h = __float22bfloat162_rn(float2{lo, hi});   // v_cvt_pk_bf16_f32
    return *reinterpret_cast<unsigned*>(&h);
}

// ---------------- kernel 2: sampling -> Xoff^T bf16, + merged filter cvt ----------
__global__ __launch_bounds__(256) void sample_kernel(const float* __restrict__ x,
                                                     const float* __restrict__ tf,
                                                     const float* __restrict__ off,
                                                     unsigned short* __restrict__ xt,
                                                     unsigned short* __restrict__ wbf) {
    const int bx = blockIdx.x;
    if (bx >= SAMPLE_BLOCKS) {                 // ---- cvt path (no LDS, no barriers)
        const int o = bx - SAMPLE_BLOCKS;
        const float* fo = tf + (size_t)o * KK;
        unsigned short* wo = wbf + (size_t)o * KK;
        for (int k4 = threadIdx.x * 4; k4 < KK; k4 += 1024) {
            int n = k4 >> 8;
            int c = k4 & 255;
            us4 v;
#pragma unroll
            for (int cc = 0; cc < 4; ++cc) v[cc] = f2bf(fo[(c + cc) * 9 + n]);
            *reinterpret_cast<us4*>(wo + k4) = v;
        }
        return;
    }

    const int wid = (bx & 7) * 144 + (bx >> 3);
    const int b = wid / 72;
    const int rem = wid - b * 72;
    const int y = rem >> 1;
    const int half = rem & 1;
    const int tid = threadIdx.x;
    const float sx = 3.0f / off[2 * b + 0];
    const float sy = 3.0f / off[2 * b + 1];

    // row (i) tables: per-thread registers (block-uniform)
    int qxl[3], qxr[3]; float gxl[3], gxr[3];
    bool lok[3], rok[3];
#pragma unroll
    for (int i = 0; i < 3; ++i) {
        float px = (float)(y + 1) + (float)(i - 1) * sx;
        float pc = fminf(fmaxf(px, 0.f), 37.f);
        float fl = floorf(px);
        float ql = fminf(fmaxf(fl, 0.f), 37.f);
        float qr = fminf(fmaxf(fl + 1.f, 0.f), 37.f);
        qxl[i] = (int)ql; qxr[i] = (int)qr;
        gxl[i] = 1.f + (ql - pc);
        gxr[i] = 1.f - (qr - pc);
        lok[i] = (qxl[i] >= 1 && qxl[i] <= 36);
        rok[i] = (qxr[i] >= 1 && qxr[i] <= 36);
    }

    // column (x,j) tables in LDS
    __shared__ int   s_qyl[HH * 3], s_qyr[HH * 3];
    __shared__ float s_gyl[HH * 3], s_gyr[HH * 3];
    if (tid < HH * 3) {
        int xx = tid / 3, j = tid % 3;
        float py = (float)(xx + 1) + (float)(j - 1) * sy;
        float pc = fminf(fmaxf(py, 0.f), 37.f);
        float fl = floorf(py);
        float ql = fminf(fmaxf(fl, 0.f), 37.f);
        float qr = fminf(fmaxf(fl + 1.f, 0.f), 37.f);
        s_qyl[tid] = (int)ql; s_qyr[tid] = (int)qr;
        s_gyl[tid] = 1.f + (ql - pc);
        s_gyr[tid] = 1.f - (qr - pc);
    }

    // row-lerped tile, octet-XOR layout (R17): element (i,col,c) lives at
    //   (i*38+col)*64 + (((c>>3) ^ (col&7))<<3) + (c&7)
    __shared__ float xr[3 * 38 * 64];

    for (int chunk = 0; chunk < 2; ++chunk) {
        const int c0 = half * 128 + chunk * 64;
        __syncthreads();      // xr reusable (prev phase-2 done); covers tables iter0

        // boundary cols 0 and 37 are zero; XOR is a bijection so linear c covers all
        for (int t = tid; t < 384; t += 256) {
            int i = t / 128, r3 = t & 127;
            int col = (r3 & 64) ? 37 : 0, c = r3 & 63;
            xr[(i * 38 + col) * 64 + c] = 0.f;
        }

        // phase 1: row-lerp. tasks (i, c, colquad): coalesced float4 col-reads,
        // 4 scalar LDS writes at swizzled octets.
        const float* xb = x + (size_t)(b * CT + c0) * NP;
        for (int t = tid; t < 3 * 64 * 9; t += 256) {
            const int i = t / 576;
            const int r2 = t - i * 576;
            const int c = r2 / 9;
            const int cq = r2 - c * 9;
            const int colb = 1 + cq * 4;          // padded col of elem 0
            const float* xc = xb + c * NP;
            float4 vl = make_float4(0.f, 0.f, 0.f, 0.f);
            float4 vr = vl;
            if (lok[i]) vl = *(const float4*)(xc + (qxl[i] - 1) * WW + colb - 1);
            if (rok[i]) vr = *(const float4*)(xc + (qxr[i] - 1) * WW + colb - 1);
            float v[4] = { gxl[i] * vl.x + gxr[i] * vr.x, gxl[i] * vl.y + gxr[i] * vr.y,
                           gxl[i] * vl.z + gxr[i] * vr.z, gxl[i] * vl.w + gxr[i] * vr.w };
            const int ch = c >> 3, co = c & 7;
#pragma unroll
            for (int k = 0; k < 4; ++k) {
                const int col = colb + k;
                xr[(i * 38 + col) * 64 + ((ch ^ (col & 7)) << 3) + co] = v[k];
            }
        }
        __syncthreads();

        // phase 2 (rebalanced, swizzled reads): subtasks (i, xi, c8), 3 taps x 8 ch.
        for (int t = tid; t < 3 * 36 * 8; t += 256) {
            const int i = t / 288;
            const int r = t - i * 288;
            const int xi = r >> 3;
            const int c8 = r & 7;
            unsigned short* op = xt + ((size_t)b * NP + y * WW + xi) * KK + c0 + c8 * 8
                               + i * 3 * 256;
#pragma unroll
            for (int j = 0; j < 3; ++j) {
                const int tq = xi * 3 + j;
                const int ql = s_qyl[tq], qr = s_qyr[tq];
                const float gl = s_gyl[tq], gr = s_gyr[tq];
                const float* L = &xr[(i * 38 + ql) * 64 + ((c8 ^ (ql & 7)) << 3)];
                const float* R = &xr[(i * 38 + qr) * 64 + ((c8 ^ (qr & 7)) << 3)];
                f32x4 L0 = *(const f32x4*)L, L1 = *(const f32x4*)(L + 4);
                f32x4 R0 = *(const f32x4*)R, R1 = *(const f32x4*)(R + 4);
                uint4v w;
                w[0] = pk2bf(gl * L0[0] + gr * R0[0], gl * L0[1] + gr * R0[1]);
                w[1] = pk2bf(gl * L0[2] + gr * R0[2], gl * L0[3] + gr * R0[3]);
                w[2] = pk2bf(gl * L1[0] + gr * R1[0], gl * L1[1] + gr * R1[1]);
                w[3] = pk2bf(gl * L1[2] + gr * R1[2], gl * L1[3] + gr * R1[3]);
                *reinterpret_cast<uint4v*>(op + j * 256) = w;
            }
        }
    }
}

// ---------------- kernel 3: MFMA GEMM, 128x64, dbuf, counted-vmcnt (R8) ----------
__global__ __launch_bounds__(256) void gemm_kernel(const unsigned short* __restrict__ wbf,
                                                   const unsigned short* __restrict__ xt,
                                                   float* __restrict__ out) {
    // 672 blocks = 8 XCD * 84; 84 per XCD = 2 b's worth (42 tiles per b)
    const int wid = (blockIdx.x & 7) * 84 + (blockIdx.x >> 3);
    const int b = wid / 42;
    const int rem = wid - b * 42;
    const int mt = rem / 21;
    const int nt = rem - mt * 21;
    const int m0 = mt * 128;
    const int p0 = nt * 64;
    const int g = b & 3;
    const int mimg = b >> 2;

    const unsigned short* Ab = wbf + (size_t)(g * OUTG + m0) * KK;
    const unsigned short* Bb = xt + (size_t)b * NP * KK;

    __shared__ __align__(16) unsigned short As[2][128 * 64];
    __shared__ __align__(16) unsigned short Bs[2][64 * 64];

    const int tid = threadIdx.x;
    const int wave = tid >> 6, lane = tid & 63;
    const int wr = wave >> 1, wc = wave & 1;
    const int l8 = lane >> 3;
    const int sgrp = (lane & 7) ^ l8;         // pre-swizzled source column group

    f32x4 acc[4][2] = {};

#define STAGE(BUF, KT) do {                                                       \
    const int k0_ = (KT) * 64;                                                    \
    _Pragma("unroll")                                                             \
    for (int ii = 0; ii < 4; ++ii) {                                              \
        const int inst = wave * 4 + ii;                                           \
        const int row = inst * 8 + l8;                                            \
        const unsigned short* srcA = Ab + (size_t)row * KK + k0_ + sgrp * 8;      \
        __builtin_amdgcn_global_load_lds(                                         \
            (const __attribute__((address_space(1))) void*)srcA,                  \
            (__attribute__((address_space(3))) void*)&As[BUF][inst * 512], 16, 0, 0); \
    }                                                                             \
    _Pragma("unroll")                                                             \
    for (int ii = 0; ii < 2; ++ii) {                                              \
        const int inst = wave * 2 + ii;                                           \
        const int row = inst * 8 + l8;                                            \
        int prow = p0 + row;                                                      \
        prow = prow < NP ? prow : NP - 1;                                         \
        const unsigned short* srcB = Bb + (size_t)prow * KK + k0_ + sgrp * 8;     \
        __builtin_amdgcn_global_load_lds(                                         \
            (const __attribute__((address_space(1))) void*)srcB,                  \
            (__attribute__((address_space(3))) void*)&Bs[BUF][inst * 512], 16, 0, 0); \
    }                                                                             \
} while (0)

#define COMPUTE(BUF) do {                                                         \
    _Pragma("unroll")                                                             \
    for (int kk = 0; kk < 2; ++kk) {                                              \
        short8 a[4], bfr[2];                                                      \
        const int g8 = (((kk * 4) + (lane >> 4)) ^ (lane & 7)) << 3;              \
        const int rA = wr * 64 + (lane & 15);                                     \
        const int rB = wc * 32 + (lane & 15);                                     \
        _Pragma("unroll")                                                         \
        for (int m = 0; m < 4; ++m)                                               \
            a[m] = *(const short8*)&As[BUF][(rA + m * 16) * 64 + g8];             \
        _Pragma("unroll")                                                         \
        for (int n = 0; n < 2; ++n)                                               \
            bfr[n] = *(const short8*)&Bs[BUF][(rB + n * 16) * 64 + g8];           \
        _Pragma("unroll")                                                         \
        for (int m = 0; m < 4; ++m)                                               \
            _Pragma("unroll")                                                     \
            for (int n = 0; n < 2; ++n)                                           \
                acc[m][n] = __builtin_amdgcn_mfma_f32_16x16x32_bf16(              \
                    a[m], bfr[n], acc[m][n], 0, 0, 0);                            \
    }                                                                             \
} while (0)

    STAGE(0, 0);                         // 6 loads in flight

#pragma unroll 1
    for (int kt = 0; kt < 35; ++kt) {
        STAGE((kt + 1) & 1, kt + 1);     // +6 loads -> 12 in flight
        // wait ONLY for tile kt's 6 loads; kt+1's stay in flight across barrier
        asm volatile("s_waitcnt vmcnt(6)" ::: "memory");
        __builtin_amdgcn_sched_barrier(0);
        __builtin_amdgcn_s_barrier();    // all waves' tile-kt loads landed
        COMPUTE(kt & 1);
        __builtin_amdgcn_s_barrier();    // readers done before next STAGE overwrites
    }
    asm volatile("s_waitcnt vmcnt(0)" ::: "memory");
    __builtin_amdgcn_sched_barrier(0);
    __builtin_amdgcn_s_barrier();
    COMPUTE(35 & 1);

#undef STAGE
#undef COMPUTE

    float* ob = out + ((size_t)mimg * OCH + g * OUTG) * NP;
    const int o0 = m0 + wr * 64 + ((lane >> 4) << 2);
    const int pc = p0 + wc * 32 + (lane & 15);
#pragma unroll
    for (int n = 0; n < 2; ++n) {
        int p = pc + n * 16;
        if (p >= NP) continue;
#pragma unroll
        for (int m = 0; m < 4; ++m) {
#pragma unroll
            for (int r = 0; r < 4; ++r)
                ob[(size_t)(o0 + m * 16 + r) * NP + p] = acc[m][n][r];
        }
    }
}

extern "C" void kernel_launch(void* const* d_in, const int* in_sizes, int n_in,
                              void* d_out, int out_size, void* d_ws, size_t ws_size,
                              hipStream_t stream) {
    const float* x   = (const float*)d_in[0];
    const float* tf  = (const float*)d_in[1];
    const float* off = (const float*)d_in[2];
    float* out = (float*)d_out;

    unsigned short* xt  = (unsigned short*)d_ws;                    // [16][1296][2304] bf16
    unsigned short* wbf = xt + (size_t)NB * NP * KK;                // [1024][2304] bf16

    hipLaunchKernelGGL(sample_kernel, dim3(SAMPLE_BLOCKS + OCH), dim3(256), 0, stream,
                       x, tf, off, xt, wbf);
    hipLaunchKernelGGL(gemm_kernel, dim3(672), dim3(256), 0, stream, wbf, xt, out);
}